// Round 4
// baseline (288.351 us; speedup 1.0000x reference)
//
#include <hip/hip_runtime.h>
#include <math.h>

// EM routing, hardcoded geometry: CHILD_SPACE=12, K=3, S=1 -> P=10,
// CHILD_CAPS=16, PARENT_CAPS=O=32, POSE=16, N=4, KTOT=144
#define NB     4
#define P      10
#define P2     100
#define CS     12
#define CCAPS  16
#define KTOT   144
#define O      32
#define POSE   16
#define VSZ    73728          // KTOT*O*POSE floats per (b,p)
#define EPSF   1e-9f
#define LNF    22.2222222222222222f   // 100/(144/32)
#define TWO_PI 6.28318530717958647f

#define NBP    (NB*P2)        // 400
#define RRN    (NBP*KTOT*O)   // 1,843,200 floats

__device__ float g_rr  [RRN];
__device__ float g_m1  [NBP*4*512];
__device__ float g_m2  [NBP*4*512];
__device__ float g_s   [NBP*4*32];
__device__ float g_mean[NBP*512];
__device__ float g_i2v [NBP*512];
__device__ float g_zpre[NBP*32];

// number of parents covering child coordinate x (1-D): min(x+1, 3, 12-x)
__device__ __forceinline__ int npar(int x) {
    int a = x + 1, b = CS - x;
    int m = a < 3 ? a : 3;
    return m < b ? m : b;
}

// ---------------- A: stats partials ----------------
// grid 1600 = (bp)*4 + kq. 512 threads: tid = ks*128 + q, q = o*4+c4.
// Each thread: 9 float4 vote loads (k = kq*36 + ks*9 + i).
template<bool FIRST>
__global__ __launch_bounds__(512)
void stats_kernel(const float* __restrict__ votes,
                  const float* __restrict__ acts)
{
    __shared__ __align__(16) float rrp[36 * 32];      // rr' for this k-slice
    __shared__ float act_lds[36];
    __shared__ __align__(16) float lm1[512 * 4];
    __shared__ __align__(16) float lm2[512 * 4];
    __shared__ float lss[512];

    const int tid = threadIdx.x;
    const int ks  = tid >> 7;
    const int q   = tid & 127;
    const int o   = q >> 2;
    const int blk = blockIdx.x;
    const int bp  = blk >> 2;
    const int kq  = blk & 3;
    const int p   = bp % P2;
    const int pr  = p / P, pc = p % P;
    const int k0  = kq * 36;

    if (tid < 36) act_lds[tid] = acts[bp * KTOT + k0 + tid];
    __syncthreads();

    if (tid < 288) {                 // 288 float4 = 1152 floats = 36 k x 32 o
        int kk = tid >> 3;           // local k
        float4 r4;
        if (FIRST) {
            int ka = k0 + kk;
            int kslot = ka >> 4;
            int kr = kslot / 3, kc = kslot % 3;
            float ppc = (float)(npar(pr + kr) * npar(pc + kc));
            float r = act_lds[kk] / (ppc * 32.0f + EPSF);
            r4 = make_float4(r, r, r, r);
        } else {
            r4 = ((const float4*)(g_rr + (size_t)bp * (KTOT * O) + k0 * 32))[tid];
            float a = act_lds[kk];
            r4.x *= a; r4.y *= a; r4.z *= a; r4.w *= a;
        }
        ((float4*)rrp)[tid] = r4;
    }
    __syncthreads();

    const float* vb = votes + (size_t)bp * VSZ;
    float  s  = 0.f;
    float4 m1 = make_float4(0.f, 0.f, 0.f, 0.f);
    float4 m2 = make_float4(0.f, 0.f, 0.f, 0.f);
    const int kl0 = ks * 9;
    #pragma unroll
    for (int i = 0; i < 9; ++i) {
        float  rp = rrp[(kl0 + i) * 32 + o];
        float4 v  = *(const float4*)(vb + (k0 + kl0 + i) * 512 + q * 4);
        s += rp;
        m1.x += rp * v.x;       m1.y += rp * v.y;
        m1.z += rp * v.z;       m1.w += rp * v.w;
        m2.x += rp * v.x * v.x; m2.y += rp * v.y * v.y;
        m2.z += rp * v.z * v.z; m2.w += rp * v.w * v.w;
    }

    ((float4*)lm1)[tid] = m1;
    ((float4*)lm2)[tid] = m2;
    lss[tid] = s;
    __syncthreads();

    if (tid < 128) {
        float4 a, b;
        a = ((float4*)lm1)[tid];       b = ((float4*)lm1)[tid + 128];
        m1.x = a.x + b.x; m1.y = a.y + b.y; m1.z = a.z + b.z; m1.w = a.w + b.w;
        a = ((float4*)lm1)[tid + 256]; b = ((float4*)lm1)[tid + 384];
        m1.x += a.x + b.x; m1.y += a.y + b.y; m1.z += a.z + b.z; m1.w += a.w + b.w;
        a = ((float4*)lm2)[tid];       b = ((float4*)lm2)[tid + 128];
        m2.x = a.x + b.x; m2.y = a.y + b.y; m2.z = a.z + b.z; m2.w = a.w + b.w;
        a = ((float4*)lm2)[tid + 256]; b = ((float4*)lm2)[tid + 384];
        m2.x += a.x + b.x; m2.y += a.y + b.y; m2.z += a.z + b.z; m2.w += a.w + b.w;
        s = lss[tid] + lss[tid + 128] + lss[tid + 256] + lss[tid + 384];

        ((float4*)g_m1)[blk * 128 + tid] = m1;
        ((float4*)g_m2)[blk * 128 + tid] = m2;
        if ((tid & 3) == 0) g_s[blk * 32 + (tid >> 2)] = s;
    }
}

// ---------------- B: finish stats ----------------
// grid 400 (bp), 128 threads: tid = o*4 + c4 (thread owns pose quad c4).
template<bool LAST>
__global__ __launch_bounds__(128)
void finish_kernel(const float* __restrict__ beta_v,
                   const float* __restrict__ beta_a,
                   float* __restrict__ out, float lam)
{
    __shared__ float cost_lds[O];

    const int tid = threadIdx.x;
    const int o   = tid >> 2;
    const int c4  = tid & 3;
    const int bp  = blockIdx.x;

    float4 m1 = make_float4(0.f, 0.f, 0.f, 0.f);
    float4 m2 = make_float4(0.f, 0.f, 0.f, 0.f);
    float  s  = 0.f;
    #pragma unroll
    for (int kq = 0; kq < 4; ++kq) {
        float4 a = ((const float4*)g_m1)[(bp * 4 + kq) * 128 + tid];
        float4 b = ((const float4*)g_m2)[(bp * 4 + kq) * 128 + tid];
        m1.x += a.x; m1.y += a.y; m1.z += a.z; m1.w += a.w;
        m2.x += b.x; m2.y += b.y; m2.z += b.z; m2.w += b.w;
        s += g_s[(bp * 4 + kq) * 32 + o];
    }

    float denom = s + EPSF;
    float4 mean, var, i2;
    mean.x = m1.x / denom; mean.y = m1.y / denom;
    mean.z = m1.z / denom; mean.w = m1.w / denom;
    var.x = fmaxf(m2.x / denom - mean.x * mean.x, 1e-30f);
    var.y = fmaxf(m2.y / denom - mean.y * mean.y, 1e-30f);
    var.z = fmaxf(m2.z / denom - mean.z * mean.z, 1e-30f);
    var.w = fmaxf(m2.w / denom - mean.w * mean.w, 1e-30f);
    i2.x = 0.5f / var.x; i2.y = 0.5f / var.y;
    i2.z = 0.5f / var.z; i2.w = 0.5f / var.w;

    // sum over pose of log(var+eps) (cost) and log(2pi var) (zz prefactor)
    float lve = logf(var.x + EPSF) + logf(var.y + EPSF)
              + logf(var.z + EPSF) + logf(var.w + EPSF);
    float lv2 = logf(TWO_PI * var.x) + logf(TWO_PI * var.y)
              + logf(TWO_PI * var.z) + logf(TWO_PI * var.w);
    lve += __shfl_xor(lve, 1); lve += __shfl_xor(lve, 2);
    lv2 += __shfl_xor(lv2, 1); lv2 += __shfl_xor(lv2, 2);

    if (c4 == 0)
        cost_lds[o] = (16.f * beta_v[o] + 0.5f * lve) * s * LNF;
    __syncthreads();

    float cm = 0.f;
    #pragma unroll
    for (int i = 0; i < O; ++i) cm += cost_lds[i];
    cm *= (1.0f / 32.0f);
    float sq = 0.f;
    #pragma unroll
    for (int i = 0; i < O; ++i) { float d = cost_lds[i] - cm; sq += d * d; }
    float cstd = sqrtf(sq * (1.0f / 32.0f));
    float aj = 1.f / (1.f + expf(-lam * (beta_a[o] + (cm - cost_lds[o]) / (cstd + EPSF))));

    if (LAST) {
        ((float4*)out)[bp * 128 + tid] = mean;          // poses
        if (c4 == 0) out[(size_t)NBP * 512 + bp * 32 + o] = aj;
    } else {
        ((float4*)g_mean)[bp * 128 + tid] = mean;
        ((float4*)g_i2v)[bp * 128 + tid]  = i2;
        if (c4 == 0) g_zpre[bp * 32 + o] = logf(aj + EPSF) - 0.5f * lv2;
    }
}

// ---------------- E': fused o_p0 + segment softmax ----------------
// grid 2304 = (b*144 + child)*4 + ccq. 128 threads: tid = ccl*32 + o,
// cc = ccq*4 + ccl. Each thread handles <=9 parent slots for its (cc,o).
__global__ __launch_bounds__(128)
void estep_kernel(const float* __restrict__ votes)
{
    const int tid = threadIdx.x;
    const int o   = tid & 31;
    const int ccl = tid >> 5;
    const int blk = blockIdx.x;
    const int ccq = blk & 3;
    const int bc  = blk >> 2;
    const int b   = bc / (CS * CS);
    const int c   = bc % (CS * CS);
    const int cr  = c / CS, cl = c % CS;
    const int cc  = ccq * 4 + ccl;

    float zz[9];
    float vmax = -1e30f;
    #pragma unroll
    for (int kr = 0; kr < 3; ++kr) {
        int prr = cr - kr;
        #pragma unroll
        for (int kc = 0; kc < 3; ++kc) {
            int pcc = cl - kc;
            int si = kr * 3 + kc;
            float z = -1e30f;
            if (prr >= 0 && prr <= 9 && pcc >= 0 && pcc <= 9) {
                int bpp = b * P2 + prr * P + pcc;
                const float* st = g_mean + bpp * 512 + o * 16;
                const float* iv = g_i2v  + bpp * 512 + o * 16;
                const float* vv = votes + (size_t)bpp * VSZ
                                  + (si * CCAPS + cc) * 512 + o * 16;
                float t = 0.f;
                #pragma unroll
                for (int j = 0; j < 4; ++j) {
                    float4 v = *(const float4*)(vv + j * 4);
                    float4 m = *(const float4*)(st + j * 4);
                    float4 w = *(const float4*)(iv + j * 4);
                    float dx = v.x - m.x, dy = v.y - m.y;
                    float dz = v.z - m.z, dw = v.w - m.w;
                    t += dx * dx * w.x + dy * dy * w.y
                       + dz * dz * w.z + dw * dw * w.w;
                }
                z = g_zpre[bpp * 32 + o] - t;
            }
            zz[si] = z;
            vmax = fmaxf(vmax, z);
        }
    }
    vmax = fmaxf(vmax, __shfl_xor(vmax, 1));
    vmax = fmaxf(vmax, __shfl_xor(vmax, 2));
    vmax = fmaxf(vmax, __shfl_xor(vmax, 4));
    vmax = fmaxf(vmax, __shfl_xor(vmax, 8));
    vmax = fmaxf(vmax, __shfl_xor(vmax, 16));   // max over o (per cc)

    float ps = 0.f;
    #pragma unroll
    for (int si = 0; si < 9; ++si) {
        float e = (zz[si] > -1e29f) ? expf(zz[si] - vmax) : 0.f;
        zz[si] = e;
        ps += e;
    }
    ps += __shfl_xor(ps, 1);
    ps += __shfl_xor(ps, 2);
    ps += __shfl_xor(ps, 4);
    ps += __shfl_xor(ps, 8);
    ps += __shfl_xor(ps, 16);                   // sum over o (per cc)
    float inv = 1.0f / ps;

    #pragma unroll
    for (int kr = 0; kr < 3; ++kr) {
        int prr = cr - kr;
        #pragma unroll
        for (int kc = 0; kc < 3; ++kc) {
            int pcc = cl - kc;
            int si = kr * 3 + kc;
            if (prr >= 0 && prr <= 9 && pcc >= 0 && pcc <= 9) {
                int bpp = b * P2 + prr * P + pcc;
                g_rr[(size_t)bpp * (KTOT * O) + (si * CCAPS + cc) * 32 + o]
                    = zz[si] * inv;
            }
        }
    }
}

extern "C" void kernel_launch(void* const* d_in, const int* in_sizes, int n_in,
                              void* d_out, int out_size, void* d_ws, size_t ws_size,
                              hipStream_t stream)
{
    (void)in_sizes; (void)n_in; (void)out_size; (void)d_ws; (void)ws_size;

    const float* votes = (const float*)d_in[0];
    const float* acts  = (const float*)d_in[1];
    const float* bv    = (const float*)d_in[2];
    const float* ba    = (const float*)d_in[3];
    float* out = (float*)d_out;

    const float lam0 = 0.01f * (1.0f - 0.95f);
    const float lam1 = 0.01f * (1.0f - 0.95f * 0.95f);
    const float lam2 = 0.01f * (1.0f - 0.95f * 0.95f * 0.95f);

    stats_kernel<true ><<<dim3(NBP * 4), dim3(512), 0, stream>>>(votes, acts);
    finish_kernel<false><<<dim3(NBP), dim3(128), 0, stream>>>(bv, ba, out, lam0);
    estep_kernel<<<dim3(NB * CS * CS * 4), dim3(128), 0, stream>>>(votes);

    stats_kernel<false><<<dim3(NBP * 4), dim3(512), 0, stream>>>(votes, acts);
    finish_kernel<false><<<dim3(NBP), dim3(128), 0, stream>>>(bv, ba, out, lam1);
    estep_kernel<<<dim3(NB * CS * CS * 4), dim3(128), 0, stream>>>(votes);

    stats_kernel<false><<<dim3(NBP * 4), dim3(512), 0, stream>>>(votes, acts);
    finish_kernel<true ><<<dim3(NBP), dim3(128), 0, stream>>>(bv, ba, out, lam2);
}